// Round 8
// baseline (236.911 us; speedup 1.0000x reference)
//
#include <hip/hip_runtime.h>

// IF neuron, multi-step, hard reset:
//   h_t = x_t + v_{t-1};  s_t = (h_t - 1.0 >= 0);  v_t = s_t ? 0 : h_t
//
// R7: two-dispatch split. Single-kernel variants plateau at ~3.5 TB/s app
// bytes because loads and stores share the in-order vmcnt queue and phases
// overlap poorly. Proven regimes on this chip: pure-store 6.7 TB/s
// (fillBuffer), pure-read ~6.3 TB/s. So:
//   Kernel A: read x, carry v, accumulate spike bits into 4x32-bit masks,
//             write only 4 MiB of masks to d_ws (vmem queue = loads only).
//   Kernel B: 2D grid (n4 x T); read masks (L2/L3-resident), expand to
//             0.0/1.0 floats, non-temporal store 128 MiB (pure-store).

typedef float    v4f __attribute__((ext_vector_type(4)));
typedef unsigned v4u __attribute__((ext_vector_type(4)));
typedef float    v2f __attribute__((ext_vector_type(2)));

template <int T>
__global__ __launch_bounds__(256) void if_bitmask_compute(
    const float* __restrict__ x,     // (T, N)
    const float* __restrict__ v0,    // (N,)
    unsigned* __restrict__ masks,    // (N,) one uint per element, bit t = spike
    long n4)                         // N/4
{
    static_assert(T % 8 == 0 && T <= 32, "");
    long g = (long)blockIdx.x * blockDim.x + threadIdx.x;
    if (g >= n4) return;

    const v4f* __restrict__ x4 = (const v4f*)x;
    v4f v = ((const v4f*)v0)[g];

    unsigned m0 = 0u, m1 = 0u, m2 = 0u, m3 = 0u;

    v4f cur[8], nxt[8];
#pragma unroll
    for (int k = 0; k < 8; ++k)
        cur[k] = x4[(long)k * n4 + g];
    __builtin_amdgcn_sched_barrier(0);

#pragma unroll
    for (int gb = 0; gb < T / 8; ++gb) {
        if (gb + 1 < T / 8) {
#pragma unroll
            for (int k = 0; k < 8; ++k)
                nxt[k] = x4[(long)((gb + 1) * 8 + k) * n4 + g];
        }
        __builtin_amdgcn_sched_barrier(0);
#pragma unroll
        for (int k = 0; k < 8; ++k) {
            const int t = gb * 8 + k;
            float h0 = cur[k].x + v.x;
            float h1 = cur[k].y + v.y;
            float h2 = cur[k].z + v.z;
            float h3 = cur[k].w + v.w;
            bool s0 = (h0 - 1.0f) >= 0.0f;
            bool s1 = (h1 - 1.0f) >= 0.0f;
            bool s2 = (h2 - 1.0f) >= 0.0f;
            bool s3 = (h3 - 1.0f) >= 0.0f;
            m0 |= s0 ? (1u << t) : 0u;
            m1 |= s1 ? (1u << t) : 0u;
            m2 |= s2 ? (1u << t) : 0u;
            m3 |= s3 ? (1u << t) : 0u;
            v.x = s0 ? 0.0f : h0;
            v.y = s1 ? 0.0f : h1;
            v.z = s2 ? 0.0f : h2;
            v.w = s3 ? 0.0f : h3;
        }
        if (gb + 1 < T / 8) {
#pragma unroll
            for (int k = 0; k < 8; ++k)
                cur[k] = nxt[k];
        }
        __builtin_amdgcn_sched_barrier(0);
    }

    v4u mm;
    mm.x = m0; mm.y = m1; mm.z = m2; mm.w = m3;
    __builtin_nontemporal_store(mm, &((v4u*)masks)[g]);
}

__global__ __launch_bounds__(256) void if_bitmask_expand(
    const unsigned* __restrict__ masks,  // (N,)
    float* __restrict__ out,             // (T, N)
    long n4)                             // N/4
{
    long g = (long)blockIdx.x * blockDim.x + threadIdx.x;
    if (g >= n4) return;
    const unsigned t = blockIdx.y;

    v4u m = ((const v4u*)masks)[g];
    v4f s;
    s.x = ((m.x >> t) & 1u) ? 1.0f : 0.0f;
    s.y = ((m.y >> t) & 1u) ? 1.0f : 0.0f;
    s.z = ((m.z >> t) & 1u) ? 1.0f : 0.0f;
    s.w = ((m.w >> t) & 1u) ? 1.0f : 0.0f;
    __builtin_nontemporal_store(s, &((v4f*)out)[(long)t * n4 + g]);
}

// Fallbacks for shapes the fast path doesn't cover.
__global__ __launch_bounds__(256) void if_node_f2_generic(
    const float* __restrict__ x, const float* __restrict__ v0,
    float* __restrict__ out, long n2, int T)
{
    long i = (long)blockIdx.x * blockDim.x + threadIdx.x;
    if (i >= n2) return;
    const v2f* x2 = (const v2f*)x;
    v2f*       o2 = (v2f*)out;
    v2f v = ((const v2f*)v0)[i];
    for (int t = 0; t < T; ++t) {
        v2f xv = x2[(long)t * n2 + i];
        float hx = xv.x + v.x;
        float hy = xv.y + v.y;
        bool sx = (hx - 1.0f) >= 0.0f;
        bool sy = (hy - 1.0f) >= 0.0f;
        v2f s;
        s.x = sx ? 1.0f : 0.0f;
        s.y = sy ? 1.0f : 0.0f;
        v.x = sx ? 0.0f : hx;
        v.y = sy ? 0.0f : hy;
        o2[(long)t * n2 + i] = s;
    }
}

__global__ __launch_bounds__(256) void if_node_scalar(
    const float* __restrict__ x, const float* __restrict__ v0,
    float* __restrict__ out, long n, int T)
{
    long i = (long)blockIdx.x * blockDim.x + threadIdx.x;
    if (i >= n) return;
    float v = v0[i];
    for (int t = 0; t < T; ++t) {
        float h = x[(long)t * n + i] + v;
        bool s = (h - 1.0f) >= 0.0f;
        out[(long)t * n + i] = s ? 1.0f : 0.0f;
        v = s ? 0.0f : h;
    }
}

extern "C" void kernel_launch(void* const* d_in, const int* in_sizes, int n_in,
                              void* d_out, int out_size, void* d_ws, size_t ws_size,
                              hipStream_t stream) {
    const float* x  = (const float*)d_in[0];   // (T, B, D) fp32
    const float* v0 = (const float*)d_in[1];   // (B, D) fp32
    float* out = (float*)d_out;                // (T, B, D) fp32

    long n = in_sizes[1];                      // B*D
    int  T = (int)(in_sizes[0] / n);           // 32

    int block = 256;
    bool fast = (T == 32) && ((n & 3) == 0) &&
                (ws_size >= (size_t)n * sizeof(unsigned));

    if (fast) {
        long n4 = n >> 2;
        unsigned* masks = (unsigned*)d_ws;
        long grid = (n4 + block - 1) / block;
        if_bitmask_compute<32><<<dim3((unsigned)grid), dim3(block), 0, stream>>>(
            x, v0, masks, n4);
        if_bitmask_expand<<<dim3((unsigned)grid, 32), dim3(block), 0, stream>>>(
            masks, out, n4);
    } else if ((n & 1) == 0) {
        long n2 = n >> 1;
        long grid = (n2 + block - 1) / block;
        if_node_f2_generic<<<dim3((unsigned)grid), dim3(block), 0, stream>>>(
            x, v0, out, n2, T);
    } else {
        long grid = (n + block - 1) / block;
        if_node_scalar<<<dim3((unsigned)grid), dim3(block), 0, stream>>>(
            x, v0, out, n, T);
    }
}